// Round 12
// baseline (243.076 us; speedup 1.0000x reference)
//
#include <hip/hip_runtime.h>
#include <hip/hip_bf16.h>

// Problem constants (QREncoder: path signature depth 4 + linear head)
#define BATCH 64
#define LSEQ 256
#define CIN 7
#define CC 8           // channels incl. time
#define NSIG 4680      // 8 + 64 + 512 + 4096
#define KPAD 4736      // NSIG padded to multiple of 64
#define TSTEPS 255     // LSEQ - 1
#define ODIM 512
#define NCHUNK 16      // time chunks for sig write parallelism
#define CH 16          // steps per chunk (last chunk: 15)
#define NKT 74         // KPAD / 64 K-steps
#define BM 256
#define BN 128
#define WCVT_BLK 592   // ODIM*KPAD/8/512

typedef __attribute__((ext_vector_type(8))) unsigned short ushort8;
typedef __attribute__((ext_vector_type(8))) __bf16 bf16x8;
typedef __attribute__((ext_vector_type(4))) float f32x4;

__device__ __forceinline__ unsigned short f2bf(float x) {
    __hip_bfloat16 h = __float2bfloat16(x);   // RNE
    return *(unsigned short*)&h;
}

#define GLDS16(gp, lp)                                                      \
    __builtin_amdgcn_global_load_lds(                                       \
        (const __attribute__((address_space(1))) void*)(gp),                \
        (__attribute__((address_space(3))) void*)(lp), 16, 0, 0)

// ---------------------------------------------------------------------------
// prep kernel: scan-checkpoint part (4 blocks/batch) + W conversion part.
// ---------------------------------------------------------------------------
__global__ __launch_bounds__(512) void prep_kernel(const float* __restrict__ inp,
                                                   float* __restrict__ ckpt,
                                                   const float* __restrict__ W,
                                                   unsigned short* __restrict__ Wb,
                                                   int nb) {
    __shared__ float sDx[TSTEPS * CC];
    const int bx  = blockIdx.x;
    const int tid = threadIdx.x;

    if (bx < 4 * nb) {
        const int b = bx >> 2, q = bx & 3;
        const float* ip = inp + (size_t)b * LSEQ * CIN;
        for (int i = tid; i < TSTEPS * CC; i += 512) {
            int t = i >> 3, c = i & 7;
            sDx[i] = (c == 0) ? (1.0f / 255.0f)
                              : ip[(t + 1) * CIN + (c - 1)] - ip[t * CIN + (c - 1)];
        }
        __syncthreads();

        const int o  = q * 128 + (tid >> 2);
        const int e2 = tid & 3;
        const int i1 = o >> 6, i2 = (o >> 3) & 7, i3 = o & 7;
        float a1 = 0.0f, a2 = 0.0f, a3 = 0.0f, a4a = 0.0f, a4b = 0.0f;

        for (int t = 0; t < 240; ++t) {
            const float* v = &sDx[t * CC];
            const float va = v[i1], vb = v[i2], vc = v[i3];
            const float vA = v[e2], vB = v[e2 + 4];
            const float e3s = va * vb * vc * (1.0f / 6.0f);
            const float T4 = e3s * 0.25f + a1 * vb * vc * (1.0f / 6.0f)
                           + a2 * vc * 0.5f + a3;
            a4a += vA * T4;
            a4b += vB * T4;
            a3 += e3s + (a1 * vb * 0.5f + a2) * vc;
            a2 += vb * (0.5f * va + a1);
            a1 += va;

            if (((t + 1) & 15) == 0) {
                const int c = ((t + 1) >> 4) - 1;   // 0..14
                float* cp = ckpt + ((size_t)b * 15 + c) * NSIG;
                cp[584 + o * 8 + e2]     = a4a;
                cp[584 + o * 8 + e2 + 4] = a4b;
                if (e2 == 0) {
                    cp[72 + o] = a3;
                    if ((o & 7) == 0)  cp[8 + (o >> 3)] = a2;
                    if ((o & 63) == 0) cp[i1] = a1;
                }
            }
        }
    } else {
        const int vid = (bx - 4 * nb) * 512 + tid;
        if (vid < ODIM * (KPAD / 8)) {
            const int n = vid / (KPAD / 8);
            const int g = vid - n * (KPAD / 8);
            ushort8 pk;
            if (g < NSIG / 8) {
                const float* wp = W + (size_t)n * NSIG + g * 8;
                float4 f0 = *(const float4*)wp;
                float4 f1 = *(const float4*)(wp + 4);
                pk[0] = f2bf(f0.x); pk[1] = f2bf(f0.y);
                pk[2] = f2bf(f0.z); pk[3] = f2bf(f0.w);
                pk[4] = f2bf(f1.x); pk[5] = f2bf(f1.y);
                pk[6] = f2bf(f1.z); pk[7] = f2bf(f1.w);
            } else {
#pragma unroll
                for (int e = 0; e < 8; ++e) pk[e] = 0;
            }
            *(ushort8*)(Wb + (size_t)n * KPAD + g * 8) = pk;
        }
    }
}

// ---------------------------------------------------------------------------
// Scan pass B: grid (NCHUNK, nb). Block (chunk,b) loads the chunk's start
// state from ckpt (chunk 0: zeros), runs <=16 steps, writes sig rows (bf16).
// ---------------------------------------------------------------------------
__global__ __launch_bounds__(512) void sig_write_kernel(const float* __restrict__ inp,
                                                        const float* __restrict__ ckpt,
                                                        unsigned short* __restrict__ sig) {
    __shared__ float sDx[CH * CC];

    const int chunk = blockIdx.x;
    const int b     = blockIdx.y;
    const int tid   = threadIdx.x;
    const int t0    = chunk * CH;
    const int t1    = (chunk == NCHUNK - 1) ? TSTEPS : t0 + CH;

    const float* ip = inp + (size_t)b * LSEQ * CIN;
    for (int i = tid; i < (t1 - t0) * CC; i += 512) {
        int t = t0 + (i >> 3), c = i & 7;
        sDx[i] = (c == 0) ? (1.0f / 255.0f)
                          : ip[(t + 1) * CIN + (c - 1)] - ip[t * CIN + (c - 1)];
    }
    __syncthreads();

    const int i1 = tid >> 6;
    const int i2 = (tid >> 3) & 7;
    const int i3 = tid & 7;

    float a1own, a2own, a3;
    float a4[8];
    if (chunk == 0) {
        a1own = a2own = a3 = 0.0f;
#pragma unroll
        for (int e = 0; e < 8; ++e) a4[e] = 0.0f;
    } else {
        const float* cp = ckpt + ((size_t)b * 15 + (chunk - 1)) * NSIG;
        a1own = cp[i1];
        a2own = cp[8 + (tid >> 3)];
        a3    = cp[72 + tid];
        float4 q0 = *(const float4*)&cp[584 + tid * 8];
        float4 q1 = *(const float4*)&cp[584 + tid * 8 + 4];
        a4[0] = q0.x; a4[1] = q0.y; a4[2] = q0.z; a4[3] = q0.w;
        a4[4] = q1.x; a4[5] = q1.y; a4[6] = q1.z; a4[7] = q1.w;
    }

    for (int t = t0; t < t1; ++t) {
        const float* v = &sDx[(t - t0) * CC];
        const float4 vlo = *(const float4*)&v[0];
        const float4 vhi = *(const float4*)&v[4];
        const float va = v[i1], vb = v[i2], vc = v[i3];
        const float e3s = va * vb * vc * (1.0f / 6.0f);
        const float T4 = e3s * 0.25f + a1own * vb * vc * (1.0f / 6.0f)
                       + a2own * vc * 0.5f + a3;
        a4[0] += vlo.x * T4; a4[1] += vlo.y * T4;
        a4[2] += vlo.z * T4; a4[3] += vlo.w * T4;
        a4[4] += vhi.x * T4; a4[5] += vhi.y * T4;
        a4[6] += vhi.z * T4; a4[7] += vhi.w * T4;
        a3 += e3s + (a1own * vb * 0.5f + a2own) * vc;
        a2own += vb * (0.5f * va + a1own);
        a1own += va;

        unsigned short* row = sig + ((size_t)b * TSTEPS + t) * KPAD;
        ushort8 pack;
#pragma unroll
        for (int e = 0; e < 8; ++e) pack[e] = f2bf(a4[e]);
        *(ushort8*)(row + 584 + tid * 8) = pack;                // level 4
        row[72 + tid] = f2bf(a3);                               // level 3
        if ((tid & 63) == 0) row[i1] = f2bf(a1own);             // level 1
        if ((tid & 7) == 0) row[8 + (tid >> 3)] = f2bf(a2own);  // level 2
        if (tid >= 448 && tid < 504) row[4232 + tid] = 0;       // pad
    }
}

// ---------------------------------------------------------------------------
// MFMA GEMM (R12): B operand DIRECT global->register (no LDS for B).
// Rationale: with both operands in LDS the read traffic (128KB/tile/CU) is
// ~2x the MFMA pipe and irreducible. Wb is L2/L3-resident and the 16B
// global load at [(n)*KPAD + t*64 + ks*32 + lq*8] IS the bf16x8 fragment.
// The 4x B redundancy moves to L1 (16KB/tile working set, tight temporal
// locality). LDS now holds only A (3 x 32KB buffers): reads 768cy + stage
// 256cy ~= MFMA 1030cy -- balanced pipes.
// Schedule per tile t (cross-tile pipeline, one barrier/tile):
//   LDF afN(t) | STAGE_A(t+2) x4 | LOADB(t+1) x8  -> vmcnt(12) [B(t),A(t+1)
//   done; 12 newer stay in flight] + lgkm(4) -> MFMA ph0 -> lgkm(0) ->
//   s_barrier -> LDF afP(t+1) -> MFMA ph1.
// B register sets double-buffered (b0*/b1*, static names per rule #20).
// T2 XOR-swizzle on A (conflicts==0), XCD-grouped block swizzle, setprio.
// ---------------------------------------------------------------------------
__global__ __launch_bounds__(512) void gemm_kernel(const unsigned short* __restrict__ A,
                                                   const unsigned short* __restrict__ Wb,
                                                   const float* __restrict__ bias,
                                                   float* __restrict__ out,
                                                   int Mrows) {
    __shared__ unsigned short As[3][BM * 64];   // 3 x 32 KB (A only)

    const int tid = threadIdx.x;
    int nt, mt;
    if (gridDim.y == 64) {                     // full dispatch (256 blocks)
        const int li = blockIdx.y * 4 + blockIdx.x;
        const int x  = li & 7;                 // XCD (round-robin assumption)
        const int j  = li >> 3;                // 0..31 within XCD
        mt = x * 8 + (j >> 2);                 // 8 m-panels per XCD
        nt = j & 3;
    } else {
        nt = blockIdx.x; mt = blockIdx.y;
    }
    const int lane = tid & 63;
    const int wv   = tid >> 6;                 // 0..7
    const int wr   = wv >> 1;                  // 0..3 (M)
    const int wc   = wv & 1;                   // 0..1 (N)
    const int lr   = lane & 15;
    const int lq   = lane >> 4;                // 0..3
    const int sb   = lr & 7;                   // A read-side swizzle key

    const f32x4 z4 = {0.0f, 0.0f, 0.0f, 0.0f};
    f32x4 acc[4][4];
#pragma unroll
    for (int i = 0; i < 4; ++i)
#pragma unroll
        for (int j = 0; j < 4; ++j) acc[i][j] = z4;

    const int srow = tid >> 3;                          // 0..63
    const int gcb  = (tid & 7) ^ (srow & 7);            // pre-swizzled src blk
    const int scol = gcb * 8;

    const unsigned short* aptr[4];
#pragma unroll
    for (int i = 0; i < 4; ++i) {
        int gr = mt * BM + i * 64 + srow;
        if (gr >= Mrows) gr = 0;
        aptr[i] = A + (size_t)gr * KPAD + scol;
    }

    // B direct-global row pointers (per-lane); advance by 64 elems per tile
    const unsigned short* bRow0 = Wb + (size_t)(nt * BN + wc * 64 +  0 + lr) * KPAD + lq * 8;
    const unsigned short* bRow1 = Wb + (size_t)(nt * BN + wc * 64 + 16 + lr) * KPAD + lq * 8;
    const unsigned short* bRow2 = Wb + (size_t)(nt * BN + wc * 64 + 32 + lr) * KPAD + lq * 8;
    const unsigned short* bRow3 = Wb + (size_t)(nt * BN + wc * 64 + 48 + lr) * KPAD + lq * 8;

    const int kel0 = ((lq)     ^ sb) * 8;               // ks=0 swizzled col (A)
    const int kel1 = ((4 + lq) ^ sb) * 8;               // ks=1 swizzled col (A)
    const int aoff = (wr * 64 + lr) * 64;

#define STAGE_A(BUF, koff)                                                  \
    do {                                                                    \
        _Pragma("unroll")                                                   \
        for (int i_ = 0; i_ < 4; ++i_)                                      \
            GLDS16(aptr[i_] + (koff),                                       \
                   ((char*)As[BUF]) + i_ * 8192 + tid * 16);                \
    } while (0)

#define LOADB(BP, BNv)                                                      \
    do {                                                                    \
        BP[0]  = *(const bf16x8*)(bRow0);                                   \
        BNv[0] = *(const bf16x8*)(bRow0 + 32);                              \
        BP[1]  = *(const bf16x8*)(bRow1);                                   \
        BNv[1] = *(const bf16x8*)(bRow1 + 32);                              \
        BP[2]  = *(const bf16x8*)(bRow2);                                   \
        BNv[2] = *(const bf16x8*)(bRow2 + 32);                              \
        BP[3]  = *(const bf16x8*)(bRow3);                                   \
        BNv[3] = *(const bf16x8*)(bRow3 + 32);                              \
        bRow0 += 64; bRow1 += 64; bRow2 += 64; bRow3 += 64;                 \
    } while (0)

#define MFMA16(AF, BF)                                                      \
    do {                                                                    \
        _Pragma("unroll")                                                   \
        for (int im_ = 0; im_ < 4; ++im_)                                   \
            _Pragma("unroll")                                               \
            for (int jm_ = 0; jm_ < 4; ++jm_)                               \
                acc[im_][jm_] = __builtin_amdgcn_mfma_f32_16x16x32_bf16(    \
                    AF[im_], BF[jm_], acc[im_][jm_], 0, 0, 0);              \
    } while (0)

#define LDF(DST, BUF, KEL)                                                  \
    do {                                                                    \
        _Pragma("unroll")                                                   \
        for (int l_ = 0; l_ < 4; ++l_)                                      \
            DST[l_] = *(const bf16x8*)&As[BUF][aoff + l_ * 1024 + (KEL)];   \
    } while (0)

    bf16x8 afP[4], afN[4];
    bf16x8 b0P[4], b0N[4], b1P[4], b1N[4];

    // prologue: A tiles 0,1 + B tile 0 in flight; wait A(0) (12 newer remain)
    STAGE_A(0, 0);
    STAGE_A(1, 64);
    LOADB(b0P, b0N);                 // B(0); pointers now at tile 1
    asm volatile("s_waitcnt vmcnt(12)" ::: "memory");
    __builtin_amdgcn_sched_barrier(0);
    __builtin_amdgcn_s_barrier();
    __builtin_amdgcn_sched_barrier(0);
    LDF(afP, 0, kel0);
    __builtin_amdgcn_sched_barrier(0);

    int koff = 128;   // global K offset of tile t+2

#define TILE_FULL(CUR, NXT, NN, BPc, BNc, BPn, BNn)                         \
    {                                                                       \
        LDF(afN, CUR, kel1);                                                \
        STAGE_A(NN, koff);                                                  \
        koff += 64;                                                         \
        LOADB(BPn, BNn);                                                    \
        __builtin_amdgcn_sched_barrier(0);                                  \
        asm volatile("s_waitcnt vmcnt(12) lgkmcnt(4)" ::: "memory");        \
        __builtin_amdgcn_sched_barrier(0);                                  \
        __builtin_amdgcn_s_setprio(1);                                      \
        MFMA16(afP, BPc);                                                   \
        __builtin_amdgcn_s_setprio(0);                                      \
        __builtin_amdgcn_sched_barrier(0);                                  \
        asm volatile("s_waitcnt lgkmcnt(0)" ::: "memory");                  \
        __builtin_amdgcn_sched_barrier(0);                                  \
        __builtin_amdgcn_s_barrier();                                       \
        __builtin_amdgcn_sched_barrier(0);                                  \
        LDF(afP, NXT, kel0);                                                \
        __builtin_amdgcn_sched_barrier(0);                                  \
        __builtin_amdgcn_s_setprio(1);                                      \
        MFMA16(afN, BNc);                                                   \
        __builtin_amdgcn_s_setprio(0);                                      \
        __builtin_amdgcn_sched_barrier(0);                                  \
    }

    for (int tb = 0; tb < 12; ++tb) {          // tiles 0..71 (6 per iter)
        TILE_FULL(0, 1, 2, b0P, b0N, b1P, b1N);
        TILE_FULL(1, 2, 0, b1P, b1N, b0P, b0N);
        TILE_FULL(2, 0, 1, b0P, b0N, b1P, b1N);
        TILE_FULL(0, 1, 2, b1P, b1N, b0P, b0N);
        TILE_FULL(1, 2, 0, b0P, b0N, b1P, b1N);
        TILE_FULL(2, 0, 1, b1P, b1N, b0P, b0N);
    }

    {   // tile 72 (buf 0, B set 0): no staging, drain everything
        LDF(afN, 0, kel1);
        __builtin_amdgcn_sched_barrier(0);
        asm volatile("s_waitcnt vmcnt(0) lgkmcnt(4)" ::: "memory");
        __builtin_amdgcn_sched_barrier(0);
        __builtin_amdgcn_s_setprio(1);
        MFMA16(afP, b0P);
        __builtin_amdgcn_s_setprio(0);
        __builtin_amdgcn_sched_barrier(0);
        asm volatile("s_waitcnt lgkmcnt(0)" ::: "memory");
        __builtin_amdgcn_sched_barrier(0);
        __builtin_amdgcn_s_barrier();
        __builtin_amdgcn_sched_barrier(0);
        LDF(afP, 1, kel0);
        __builtin_amdgcn_sched_barrier(0);
        __builtin_amdgcn_s_setprio(1);
        MFMA16(afN, b0N);
        __builtin_amdgcn_s_setprio(0);
        __builtin_amdgcn_sched_barrier(0);
    }
    {   // tile 73 (buf 1, B set 1): last
        LDF(afN, 1, kel1);
        __builtin_amdgcn_sched_barrier(0);
        asm volatile("s_waitcnt lgkmcnt(4)" ::: "memory");
        __builtin_amdgcn_sched_barrier(0);
        __builtin_amdgcn_s_setprio(1);
        MFMA16(afP, b1P);
        __builtin_amdgcn_s_setprio(0);
        __builtin_amdgcn_sched_barrier(0);
        asm volatile("s_waitcnt lgkmcnt(0)" ::: "memory");
        __builtin_amdgcn_sched_barrier(0);
        __builtin_amdgcn_s_setprio(1);
        MFMA16(afN, b1N);
        __builtin_amdgcn_s_setprio(0);
        __builtin_amdgcn_sched_barrier(0);
    }

    float bn[4];
#pragma unroll
    for (int j = 0; j < 4; ++j)
        bn[j] = bias[nt * BN + wc * 64 + j * 16 + lr];

#pragma unroll
    for (int i = 0; i < 4; ++i) {
        const int mbase = mt * BM + wr * 64 + i * 16 + lq * 4;
#pragma unroll
        for (int r = 0; r < 4; ++r) {
            const int m = mbase + r;
            if (m < Mrows) {
#pragma unroll
                for (int j = 0; j < 4; ++j) {
                    const int n = nt * BN + wc * 64 + j * 16 + lr;
                    out[(size_t)m * ODIM + n] = acc[i][j][r] + bn[j];
                }
            }
        }
    }
#undef STAGE_A
#undef LOADB
#undef MFMA16
#undef LDF
#undef TILE_FULL
}

extern "C" void kernel_launch(void* const* d_in, const int* in_sizes, int n_in,
                              void* d_out, int out_size, void* d_ws, size_t ws_size,
                              hipStream_t stream) {
    const float* inp  = (const float*)d_in[0];
    const float* W    = (const float*)d_in[1];
    const float* bias = (const float*)d_in[2];
    float* out = (float*)d_out;

    const size_t wbBytes = (size_t)ODIM * KPAD * sizeof(unsigned short);
    const size_t sigPB   = (size_t)TSTEPS * KPAD * sizeof(unsigned short); // 2.42 MB
    const size_t ckptPB  = (size_t)15 * NSIG * sizeof(float);              // 0.28 MB
    const size_t perB    = sigPB + ckptPB;

    int nbMax = (int)((ws_size - wbBytes) / perB);
    if (nbMax > BATCH) nbMax = BATCH;
    if (nbMax < 1) nbMax = 1;

    unsigned short* sig  = (unsigned short*)d_ws;
    float*          ckpt = (float*)((char*)d_ws + (size_t)nbMax * sigPB);
    unsigned short* Wb   = (unsigned short*)((char*)d_ws + (ws_size - wbBytes));

    for (int b0 = 0; b0 < BATCH; b0 += nbMax) {
        const int nb = (b0 + nbMax <= BATCH) ? nbMax : (BATCH - b0);
        const int Mrows = nb * TSTEPS;
        const float* ipb = inp + (size_t)b0 * LSEQ * CIN;
        prep_kernel<<<4 * nb + WCVT_BLK, 512, 0, stream>>>(ipb, ckpt, W, Wb, nb);
        sig_write_kernel<<<dim3(NCHUNK, nb), 512, 0, stream>>>(ipb, ckpt, sig);
        gemm_kernel<<<dim3(ODIM / BN, (Mrows + BM - 1) / BM), 512, 0, stream>>>(
            sig, Wb, bias, out + (size_t)b0 * TSTEPS * ODIM, Mrows);
    }
}

// Round 13
// 186.885 us; speedup vs baseline: 1.3007x; 1.3007x over previous
//
#include <hip/hip_runtime.h>
#include <hip/hip_bf16.h>

// QREncoder: path signature depth 4 + linear head.
// R13 architecture: level-4 is never materialized. Δa4 = T4⊗v (rank-1), so we
// store T4 [b][256][512] f32 + v [b][256][8] f32 + Δ(levels1-3) bf16, run the
// GEMM on INCREMENT rows (L4 A-fragments reconstructed in registers from
// T4×v), and prefix-sum the accumulator over t in the epilogue.
#define BATCH 64
#define LSEQ 256
#define CIN 7
#define CC 8
#define NSIG 4680
#define TSTEPS 255
#define ODIM 512
#define NCHUNK 16
#define CH 16
#define ROWS 256        // padded rows per batch (row 255 = zeros)
#define DCOLS 640       // Δ123 width: 72 + 512 + 56 pad
#define KPAD 4736       // 640 + 4096
#define NT123 20        // L123 K-tiles (32 wide)
#define NTILES 84       // 20 + 64 L4 tiles (64 wide)
#define WCVT_BLK 592    // 512*4736/8/512

typedef __attribute__((ext_vector_type(8))) unsigned short ushort8;
typedef __attribute__((ext_vector_type(8))) __bf16 bf16x8;
typedef __attribute__((ext_vector_type(4))) float f32x4;

__device__ __forceinline__ unsigned short f2bf(float x) {
    __hip_bfloat16 h = __float2bfloat16(x);   // RNE
    return *(unsigned short*)&h;
}

#define GLDS16(gp, lp)                                                      \
    __builtin_amdgcn_global_load_lds(                                       \
        (const __attribute__((address_space(1))) void*)(gp),                \
        (__attribute__((address_space(3))) void*)(lp), 16, 0, 0)

// ---------------------------------------------------------------------------
// prep: blocks [0,nb): a1/a2/a3-only scan per batch, ckpt (584 f32) at
// t=16..240. blocks [nb, nb+592): W fp32 -> bf16 with column PERMUTATION:
// Wb[n][k<584] = W[n][k] (levels 1-3); [584..640) = 0; [640+q] = W[n][584+q].
// ---------------------------------------------------------------------------
__global__ __launch_bounds__(512) void prep_kernel(const float* __restrict__ inp,
                                                   float* __restrict__ ckpt,
                                                   const float* __restrict__ W,
                                                   unsigned short* __restrict__ Wb,
                                                   int nb) {
    __shared__ float sDx[TSTEPS * CC];
    const int bx  = blockIdx.x;
    const int tid = threadIdx.x;

    if (bx < nb) {
        const int b = bx;
        const float* ip = inp + (size_t)b * LSEQ * CIN;
        for (int i = tid; i < TSTEPS * CC; i += 512) {
            int t = i >> 3, c = i & 7;
            sDx[i] = (c == 0) ? (1.0f / 255.0f)
                              : ip[(t + 1) * CIN + (c - 1)] - ip[t * CIN + (c - 1)];
        }
        __syncthreads();
        const int i1 = tid >> 6, i2 = (tid >> 3) & 7, i3 = tid & 7;
        float a1 = 0.0f, a2 = 0.0f, a3 = 0.0f;
        for (int t = 0; t < 240; ++t) {
            const float* v = &sDx[t * CC];
            const float va = v[i1], vb = v[i2], vc = v[i3];
            const float e3s = va * vb * vc * (1.0f / 6.0f);
            a3 += e3s + (a1 * vb * 0.5f + a2) * vc;
            a2 += vb * (0.5f * va + a1);
            a1 += va;
            if (((t + 1) & 15) == 0) {
                const int c = ((t + 1) >> 4) - 1;
                float* cp = ckpt + ((size_t)b * 15 + c) * 584;
                if ((tid & 63) == 0) cp[i1] = a1;
                if ((tid & 7) == 0) cp[8 + (tid >> 3)] = a2;
                cp[72 + tid] = a3;
            }
        }
    } else {
        const int vid = (bx - nb) * 512 + tid;
        if (vid < ODIM * (KPAD / 8)) {
            const int n = vid / (KPAD / 8);
            const int g = vid - n * (KPAD / 8);
            ushort8 pk;
            const float* wp = nullptr;
            if (g < 73)      wp = W + (size_t)n * NSIG + g * 8;
            else if (g >= 80) wp = W + (size_t)n * NSIG + 584 + (g - 80) * 8;
            if (wp) {
                float4 f0 = *(const float4*)wp;
                float4 f1 = *(const float4*)(wp + 4);
                pk[0] = f2bf(f0.x); pk[1] = f2bf(f0.y);
                pk[2] = f2bf(f0.z); pk[3] = f2bf(f0.w);
                pk[4] = f2bf(f1.x); pk[5] = f2bf(f1.y);
                pk[6] = f2bf(f1.z); pk[7] = f2bf(f1.w);
            } else {
#pragma unroll
                for (int e = 0; e < 8; ++e) pk[e] = 0;
            }
            *(ushort8*)(Wb + (size_t)n * KPAD + g * 8) = pk;
        }
    }
}

// ---------------------------------------------------------------------------
// delta: grid (NCHUNK, nb). Loads ckpt, runs <=16 steps, writes PER-STEP
// INCREMENTS: T4 row (512 f32, coalesced), Δ123 row (bf16, 640 w/ pad),
// v row (8 f32). Chunk 15 zeroes padded row 255.
// ---------------------------------------------------------------------------
__global__ __launch_bounds__(512) void delta_kernel(const float* __restrict__ inp,
                                                    const float* __restrict__ ckpt,
                                                    unsigned short* __restrict__ sigD,
                                                    float* __restrict__ T4g,
                                                    float* __restrict__ vtab) {
    __shared__ float sDx[CH * CC];
    const int chunk = blockIdx.x;
    const int b     = blockIdx.y;
    const int tid   = threadIdx.x;
    const int t0    = chunk * CH;
    const int t1    = (chunk == NCHUNK - 1) ? TSTEPS : t0 + CH;

    const float* ip = inp + (size_t)b * LSEQ * CIN;
    for (int i = tid; i < (t1 - t0) * CC; i += 512) {
        int t = t0 + (i >> 3), c = i & 7;
        sDx[i] = (c == 0) ? (1.0f / 255.0f)
                          : ip[(t + 1) * CIN + (c - 1)] - ip[t * CIN + (c - 1)];
    }
    __syncthreads();

    const int i1 = tid >> 6, i2 = (tid >> 3) & 7, i3 = tid & 7;
    float a1, a2, a3;
    if (chunk == 0) {
        a1 = a2 = a3 = 0.0f;
    } else {
        const float* cp = ckpt + ((size_t)b * 15 + (chunk - 1)) * 584;
        a1 = cp[i1];
        a2 = cp[8 + (tid >> 3)];
        a3 = cp[72 + tid];
    }

    for (int t = t0; t < t1; ++t) {
        const float* v = &sDx[(t - t0) * CC];
        const float va = v[i1], vb = v[i2], vc = v[i3];
        const float e3s = va * vb * vc * (1.0f / 6.0f);
        const float dT4 = e3s * 0.25f + a1 * vb * vc * (1.0f / 6.0f)
                        + a2 * vc * 0.5f + a3;
        const float dA3 = e3s + (a1 * vb * 0.5f + a2) * vc;
        const float dA2 = vb * (0.5f * va + a1);

        const size_t rr = (size_t)b * ROWS + t;
        T4g[rr * 512 + tid] = dT4;
        unsigned short* row = sigD + rr * DCOLS;
        row[72 + tid] = f2bf(dA3);
        if ((tid & 63) == 0) row[i1] = f2bf(va);
        if ((tid & 7) == 0) row[8 + (tid >> 3)] = f2bf(dA2);
        if (tid >= 448 && tid < 504) row[136 + tid] = 0;        // pad 584..640
        if (tid >= 504) vtab[rr * 8 + (tid - 504)] = v[tid - 504];

        a3 += dA3; a2 += dA2; a1 += va;
    }

    if (chunk == NCHUNK - 1) {                 // zero padded row 255
        const size_t rr = (size_t)b * ROWS + 255;
        T4g[rr * 512 + tid] = 0.0f;
        for (int c = tid; c < DCOLS; c += 512) sigD[rr * DCOLS + c] = 0;
        if (tid < 8) vtab[rr * 8 + tid] = 0.0f;
    }
}

// ---------------------------------------------------------------------------
// GEMM on increment rows + prefix-sum epilogue. Block = (batch b, n-tile nt),
// 8 waves (4Mx2N, wave 64x64). Tiles 0..19: Δ123 (BK=32, staged bf16, T2
// swizzle). Tiles 20..83: L4 (BK=64): B staged as before; A-fragments
// CONSTRUCTED in registers: bf16(T4[row,o] * v[row,e]) — T4 staged to LDS
// (8KB/tile, 1 gload, half-granule XOR swizzle -> 2-way-free b32 reads),
// v in 32 VGPRs (block-constant). Uniform 3 stage-ops/tile -> vmcnt(3).
// Epilogue: inclusive prefix over t per column via LDS, +bias, store.
// ---------------------------------------------------------------------------
__global__ __launch_bounds__(512) void gemm_kernel(const unsigned short* __restrict__ sigD,
                                                   const float* __restrict__ T4g,
                                                   const float* __restrict__ vtab,
                                                   const unsigned short* __restrict__ Wb,
                                                   const float* __restrict__ bias,
                                                   float* __restrict__ out) {
    __shared__ unsigned short A123[3][256 * 32];   // 48 KB
    __shared__ unsigned short Bs[3][128 * 64];     // 48 KB
    __shared__ float T4s[3][256 * 8];              // 24 KB

    const int tid = threadIdx.x;
    int nt, mt;
    if (gridDim.y == 64) {
        const int li = blockIdx.y * 4 + blockIdx.x;
        const int x  = li & 7;
        const int j  = li >> 3;
        mt = x * 8 + (j >> 2);
        nt = j & 3;
    } else {
        nt = blockIdx.x; mt = blockIdx.y;
    }
    const int b    = mt;                        // batch
    const int lane = tid & 63;
    const int wv   = tid >> 6;
    const int wr   = wv >> 1;                   // 0..3 (M)
    const int wc   = wv & 1;                    // 0..1 (N)
    const int lr   = lane & 15;
    const int lq   = lane >> 4;
    const int t4k  = (lr >> 2) & 1;             // T4 half-swizzle key

    const f32x4 z4 = {0.0f, 0.0f, 0.0f, 0.0f};
    f32x4 acc[4][4];
#pragma unroll
    for (int i = 0; i < 4; ++i)
#pragma unroll
        for (int j = 0; j < 4; ++j) acc[i][j] = z4;

    // v registers: 4 fragment rows x 8 channels (block-constant)
    float vreg[4][8];
#pragma unroll
    for (int i = 0; i < 4; ++i) {
        const float* vp = vtab + ((size_t)b * ROWS + wr * 64 + i * 16 + lr) * 8;
        float4 v0 = *(const float4*)vp;
        float4 v1 = *(const float4*)(vp + 4);
        vreg[i][0] = v0.x; vreg[i][1] = v0.y; vreg[i][2] = v0.z; vreg[i][3] = v0.w;
        vreg[i][4] = v1.x; vreg[i][5] = v1.y; vreg[i][6] = v1.z; vreg[i][7] = v1.w;
    }

    // staging lane geometry
    const int sr123  = tid >> 2;                         // 0..127
    const int scol32 = (((tid & 3) ^ (sr123 & 3)) * 8);  // pre-swizzled 16B blk
    const int sr64   = tid >> 3;                         // 0..63
    const int scol64 = (((tid & 7) ^ (sr64 & 7)) * 8);
    const int rT4    = tid >> 1;
    const int hT4    = (tid & 1) ^ ((rT4 >> 2) & 1);     // inverse-swizzled src

    // fragment read geometry
    const int kel32 = (lq ^ (lr & 3)) * 8;               // BK=32 swizzled col
    const int kel0  = ((lq) ^ (lr & 7)) * 8;             // BK=64 ks0
    const int kel1  = ((4 + lq) ^ (lr & 7)) * 8;         // BK=64 ks1

#define STAGE(TT)                                                           \
    do {                                                                    \
        const int tt_ = (TT);                                               \
        if (tt_ < NT123) {                                                  \
            const int bf_ = tt_ % 3;                                        \
            _Pragma("unroll")                                               \
            for (int i_ = 0; i_ < 2; ++i_)                                  \
                GLDS16(sigD + ((size_t)b * ROWS + i_ * 128 + sr123) * DCOLS \
                            + tt_ * 32 + scol32,                            \
                       (char*)A123[bf_] + i_ * 8192 + tid * 16);            \
            GLDS16(Wb + (size_t)(nt * 128 + sr123) * KPAD + tt_ * 32 + scol32, \
                   (char*)Bs[bf_] + tid * 16);                              \
        } else {                                                            \
            const int ot_ = tt_ - NT123;                                    \
            GLDS16(T4g + ((size_t)b * ROWS + rT4) * 512 + ot_ * 8 + hT4 * 4,\
                   (char*)T4s[ot_ % 3] + tid * 16);                         \
            _Pragma("unroll")                                               \
            for (int i_ = 0; i_ < 2; ++i_)                                  \
                GLDS16(Wb + (size_t)(nt * 128 + i_ * 64 + sr64) * KPAD      \
                            + DCOLS + ot_ * 64 + scol64,                    \
                       (char*)Bs[tt_ % 3] + i_ * 8192 + tid * 16);          \
        }                                                                   \
    } while (0)

#define MFMA16(AF, BF)                                                      \
    do {                                                                    \
        _Pragma("unroll")                                                   \
        for (int im_ = 0; im_ < 4; ++im_)                                   \
            _Pragma("unroll")                                               \
            for (int jm_ = 0; jm_ < 4; ++jm_)                               \
                acc[im_][jm_] = __builtin_amdgcn_mfma_f32_16x16x32_bf16(    \
                    AF[im_], BF[jm_], acc[im_][jm_], 0, 0, 0);              \
    } while (0)

#define LDT4(DST, BUF, KS)                                                  \
    do {                                                                    \
        _Pragma("unroll")                                                   \
        for (int l_ = 0; l_ < 4; ++l_)                                      \
            DST[l_] = *(const float*)((const char*)T4s[BUF]                 \
                + (wr * 64 + l_ * 16 + lr) * 32 + (((KS) ^ t4k) * 16) + lq * 4); \
    } while (0)

#define CONSTR(AF, T4R)                                                     \
    do {                                                                    \
        _Pragma("unroll")                                                   \
        for (int l_ = 0; l_ < 4; ++l_) {                                    \
            union { unsigned short u[8]; bf16x8 v8; } cc_;                  \
            _Pragma("unroll")                                               \
            for (int e_ = 0; e_ < 8; ++e_)                                  \
                cc_.u[e_] = f2bf(T4R[l_] * vreg[l_][e_]);                   \
            AF[l_] = cc_.v8;                                                \
        }                                                                   \
    } while (0)

    // prologue: tiles 0,1 in flight (3 ops each); wait tile 0
    STAGE(0);
    STAGE(1);
    asm volatile("s_waitcnt vmcnt(3)" ::: "memory");
    __builtin_amdgcn_sched_barrier(0);
    __builtin_amdgcn_s_barrier();
    __builtin_amdgcn_sched_barrier(0);

    for (int t = 0; t < NTILES; ++t) {
        if (t + 2 < NTILES) STAGE(t + 2);

        if (t < NT123) {
            const int bf = t % 3;
            bf16x8 af[4], bfv[4];
#pragma unroll
            for (int l = 0; l < 4; ++l)
                af[l] = *(const bf16x8*)&A123[bf][(wr * 64 + l * 16 + lr) * 32 + kel32];
#pragma unroll
            for (int l = 0; l < 4; ++l)
                bfv[l] = *(const bf16x8*)&Bs[bf][(wc * 64 + l * 16 + lr) * 32 + kel32];
            __builtin_amdgcn_sched_barrier(0);
            asm volatile("s_waitcnt lgkmcnt(0)" ::: "memory");
            __builtin_amdgcn_sched_barrier(0);
            __builtin_amdgcn_s_setprio(1);
            MFMA16(af, bfv);
            __builtin_amdgcn_s_setprio(0);
            __builtin_amdgcn_sched_barrier(0);
        } else {
            const int tb = (t - NT123) % 3, bb = t % 3;
            float t4P[4], t4N[4];
            bf16x8 bfP[4], bfN[4];
            LDT4(t4P, tb, 0);
#pragma unroll
            for (int l = 0; l < 4; ++l)
                bfP[l] = *(const bf16x8*)&Bs[bb][(wc * 64 + l * 16 + lr) * 64 + kel0];
            LDT4(t4N, tb, 1);
#pragma unroll
            for (int l = 0; l < 4; ++l)
                bfN[l] = *(const bf16x8*)&Bs[bb][(wc * 64 + l * 16 + lr) * 64 + kel1];
            __builtin_amdgcn_sched_barrier(0);
            asm volatile("s_waitcnt lgkmcnt(8)" ::: "memory");
            __builtin_amdgcn_sched_barrier(0);
            bf16x8 afP[4];
            CONSTR(afP, t4P);
            __builtin_amdgcn_s_setprio(1);
            MFMA16(afP, bfP);
            __builtin_amdgcn_s_setprio(0);
            __builtin_amdgcn_sched_barrier(0);
            asm volatile("s_waitcnt lgkmcnt(0)" ::: "memory");
            __builtin_amdgcn_sched_barrier(0);
            bf16x8 afN[4];
            CONSTR(afN, t4N);
            __builtin_amdgcn_s_setprio(1);
            MFMA16(afN, bfN);
            __builtin_amdgcn_s_setprio(0);
            __builtin_amdgcn_sched_barrier(0);
        }

        if (t + 2 < NTILES) {
            asm volatile("s_waitcnt vmcnt(3)" ::: "memory");
            __builtin_amdgcn_sched_barrier(0);
            __builtin_amdgcn_s_barrier();
            __builtin_amdgcn_sched_barrier(0);
        } else if (t + 1 < NTILES) {
            asm volatile("s_waitcnt vmcnt(0)" ::: "memory");
            __builtin_amdgcn_sched_barrier(0);
            __builtin_amdgcn_s_barrier();
            __builtin_amdgcn_sched_barrier(0);
        }
    }

    // ---- epilogue: inclusive prefix over t (rows) per output column ----
    float (*P)[32] = (float (*)[32])(&A123[0][0]);    // 32 KB region
    float* S = (float*)(&T4s[0][0]);                  // 8 seg-sums x 32 cols
    const int colP = wc * 16 + lr;

    for (int jj = 0; jj < 4; ++jj) {
        __syncthreads();
#pragma unroll
        for (int i = 0; i < 4; ++i)
#pragma unroll
            for (int r = 0; r < 4; ++r)
                P[wr * 64 + i * 16 + lq * 4 + r][colP] = acc[i][jj][r];
        __syncthreads();
        if (tid < 256) {                        // per-(col, 32-row segment) sums
            const int c = tid & 31, s = tid >> 5;
            float ss = 0.0f;
            for (int k = 0; k < 32; ++k) ss += P[s * 32 + k][c];
            S[s * 32 + c] = ss;
        }
        __syncthreads();
        if (tid < 32) {                         // exclusive prefix of seg sums
            float run = 0.0f;
            for (int s = 0; s < 8; ++s) {
                float x = S[s * 32 + tid];
                S[s * 32 + tid] = run;
                run += x;
            }
        }
        __syncthreads();
        if (tid < 256) {                        // inclusive prefix within seg
            const int c = tid & 31, s = tid >> 5;
            float run = S[s * 32 + c];
            for (int k = 0; k < 32; ++k) {
                run += P[s * 32 + k][c];
                P[s * 32 + k][c] = run;
            }
        }
        __syncthreads();
        for (int e = tid; e < 255 * 32; e += 512) {
            const int t = e >> 5, c = e & 31;
            const int n = nt * 128 + (c >> 4) * 64 + jj * 16 + (c & 15);
            out[((size_t)(b * 255 + t)) * ODIM + n] = P[t][c] + bias[n];
        }
    }
#undef STAGE
#undef MFMA16
#undef LDT4
#undef CONSTR
}

extern "C" void kernel_launch(void* const* d_in, const int* in_sizes, int n_in,
                              void* d_out, int out_size, void* d_ws, size_t ws_size,
                              hipStream_t stream) {
    const float* inp  = (const float*)d_in[0];
    const float* W    = (const float*)d_in[1];
    const float* bias = (const float*)d_in[2];
    float* out = (float*)d_out;

    const size_t wbBytes = (size_t)ODIM * KPAD * sizeof(unsigned short);  // 4.85 MB
    const size_t sigPB   = (size_t)ROWS * DCOLS * sizeof(unsigned short); // 320 KB
    const size_t t4PB    = (size_t)ROWS * 512 * sizeof(float);            // 512 KB
    const size_t vPB     = (size_t)ROWS * 8 * sizeof(float);              // 8 KB
    const size_t ckptPB  = (size_t)15 * 584 * sizeof(float);              // 35 KB
    const size_t perB    = sigPB + t4PB + vPB + ckptPB;

    int nbMax = (int)((ws_size - wbBytes) / perB);
    if (nbMax > BATCH) nbMax = BATCH;
    if (nbMax < 1) nbMax = 1;

    unsigned short* sigD = (unsigned short*)d_ws;
    float*          T4g  = (float*)((char*)d_ws + (size_t)nbMax * sigPB);
    float*          vtab = (float*)((char*)T4g + (size_t)nbMax * t4PB);
    float*          ckpt = (float*)((char*)vtab + (size_t)nbMax * vPB);
    unsigned short* Wb   = (unsigned short*)((char*)d_ws + (ws_size - wbBytes));

    for (int b0 = 0; b0 < BATCH; b0 += nbMax) {
        const int nb = (b0 + nbMax <= BATCH) ? nbMax : (BATCH - b0);
        const float* ipb = inp + (size_t)b0 * LSEQ * CIN;
        prep_kernel<<<nb + WCVT_BLK, 512, 0, stream>>>(ipb, ckpt, W, Wb, nb);
        delta_kernel<<<dim3(NCHUNK, nb), 512, 0, stream>>>(ipb, ckpt, sigD, T4g, vtab);
        gemm_kernel<<<dim3(4, nb), 512, 0, stream>>>(
            sigD, T4g, vtab, Wb, bias, out + (size_t)b0 * TSTEPS * ODIM);
    }
}